// Round 13
// baseline (13132.863 us; speedup 1.0000x reference)
//
#include <hip/hip_runtime.h>
#include <hip/hip_bf16.h>
#include <cstdint>
#include <cstddef>

#define DEVI __device__ __forceinline__

typedef __attribute__((ext_vector_type(8))) short bf16x8;
typedef __attribute__((ext_vector_type(4))) float f32x4;
typedef unsigned short u16;
typedef unsigned int u32;
typedef unsigned long long u64;

DEVI u16 f2bf(float f) {
    u32 i = __builtin_bit_cast(u32, f);
    u32 r = (i + 0x7FFFu + ((i >> 16) & 1u)) >> 16;
    return (u16)r;
}
DEVI float sigmoidf_(float x) { return 1.0f / (1.0f + __expf(-x)); }
DEVI float tanhf_(float x) { return 2.0f / (1.0f + __expf(-2.0f * x)) - 1.0f; }
DEVI float reluf_(float x) { return x > 0.f ? x : 0.f; }

typedef const __attribute__((address_space(1))) void* gptr_t;
typedef __attribute__((address_space(3))) void* lptr_t;

DEVI void gload16(const void* g, void* l) {
    __builtin_amdgcn_global_load_lds((gptr_t)g, (lptr_t)l, 16, 0, 0);
}

__global__ void fill_const(float* __restrict__ p, int n, float v) {
    int i = blockIdx.x * 256 + threadIdx.x;
    if (i < n) p[i] = v;
}

// ---------------- fused setup: all f32->bf16 conversions in ONE launch -----
__global__ void prep_all(const float* __restrict__ x, const float* __restrict__ We1,
                         const float* __restrict__ We2, const float* __restrict__ We3,
                         const float* __restrict__ We41, const float* __restrict__ Wih,
                         const float* __restrict__ Whh, const float* __restrict__ Wf1,
                         const float* __restrict__ Wf2, u16* __restrict__ xb,
                         u16* __restrict__ We1b, u16* __restrict__ We2b,
                         u16* __restrict__ We3b, u16* __restrict__ We41b,
                         u16* __restrict__ WB, u16* __restrict__ Wf1p,
                         u16* __restrict__ Wf2p) {
    const long long T0 = 9961472, T1 = 19922944, T2 = 22020096, T3 = 22544384,
                    T4 = 22806528, T5 = 23592960, T6 = 24379392, T7 = 24403968,
                    T8 = 24436736;
    for (long long i = (long long)blockIdx.x * 256 + threadIdx.x; i < T8;
         i += (long long)gridDim.x * 256) {
        if (i < T1) {  // xb / We1b: [2048][4864] zero-padded from [2048][4860]
            long long j = (i < T0) ? i : i - T0;
            int r = (int)(j / 4864);
            int c = (int)(j - (long long)r * 4864);
            const float* s = (i < T0) ? x : We1;
            u16* d = (i < T0) ? xb : We1b;
            d[j] = (c < 4860) ? f2bf(s[(size_t)r * 4860 + c]) : (u16)0;
        } else if (i < T2) {
            int j = (int)(i - T1);
            We2b[j] = f2bf(We2[j]);
        } else if (i < T3) {
            int j = (int)(i - T2);
            We3b[j] = f2bf(We3[j]);
        } else if (i < T4) {
            int j = (int)(i - T3);
            We41b[j] = f2bf(We41[j]);
        } else if (i < T5) {  // WB[g][0:512] = Wih
            int j = (int)(i - T4);
            int g = j >> 9, k = j & 511;
            WB[(size_t)g * 1024 + k] = f2bf(Wih[j]);
        } else if (i < T6) {  // WB[g][512:1024] = Whh
            int j = (int)(i - T5);
            int g = j >> 9, k = j & 511;
            WB[(size_t)g * 1024 + 512 + k] = f2bf(Whh[j]);
        } else if (i < T7) {  // Wf1p [48][512], rows >=42 zero
            int j = (int)(i - T6);
            int r = j >> 9;
            Wf1p[j] = (r < 42) ? f2bf(Wf1[j]) : (u16)0;
        } else {  // Wf2p [512][64], k >= 42 zero
            int j = (int)(i - T7);
            int c = j >> 6, k = j & 63;
            Wf2p[j] = (k < 42) ? f2bf(Wf2[(size_t)c * 42 + k]) : (u16)0;
        }
    }
}

// ---------------- encoder GEMM: C = epi(A @ B^T + bias) (validated) --------
template <int EPI>
__global__ __launch_bounds__(256) void gemm_bt(
    const u16* __restrict__ A, int lda, const u16* __restrict__ B, int ldb,
    const float* __restrict__ bias, u16* __restrict__ C, int ldc, int ktiles,
    const float* __restrict__ eps) {
    __shared__ u16 As[128 * 64];
    __shared__ u16 Bs[128 * 64];
    const int tid = threadIdx.x;
    const int lane = tid & 63;
    const int wave = tid >> 6;
    const int m0 = blockIdx.y * 128;
    const int n0 = blockIdx.x * 128;
    const int l15 = lane & 15, lg = lane >> 4;
    const int wm = (wave >> 1) * 64, wn = (wave & 1) * 64;

    f32x4 acc[4][4];
#pragma unroll
    for (int r = 0; r < 4; r++)
#pragma unroll
        for (int c = 0; c < 4; c++) acc[r][c] = (f32x4){0.f, 0.f, 0.f, 0.f};

    for (int t = 0; t < ktiles; ++t) {
        const int k0 = t * 64;
#pragma unroll
        for (int q = 0; q < 4; ++q) {
            int chunk = q * 4 + wave;
            int o = chunk * 1024 + lane * 16;
            int row = o >> 7;
            int cb = o & 127;
            gload16((const char*)(A + (size_t)(m0 + row) * lda + k0) + cb,
                    (char*)As + chunk * 1024);
            gload16((const char*)(B + (size_t)(n0 + row) * ldb + k0) + cb,
                    (char*)Bs + chunk * 1024);
        }
        __syncthreads();
#pragma unroll
        for (int kf = 0; kf < 2; ++kf) {
            bf16x8 a[4], b[4];
#pragma unroll
            for (int r = 0; r < 4; r++)
                a[r] = *(const bf16x8*)&As[(wm + 16 * r + l15) * 64 + kf * 32 + lg * 8];
#pragma unroll
            for (int c = 0; c < 4; c++)
                b[c] = *(const bf16x8*)&Bs[(wn + 16 * c + l15) * 64 + kf * 32 + lg * 8];
#pragma unroll
            for (int r = 0; r < 4; r++)
#pragma unroll
                for (int c = 0; c < 4; c++)
                    acc[r][c] = __builtin_amdgcn_mfma_f32_16x16x32_bf16(
                        a[r], b[c], acc[r][c], 0, 0, 0);
        }
        __syncthreads();
    }
#pragma unroll
    for (int r = 0; r < 4; r++) {
#pragma unroll
        for (int c = 0; c < 4; c++) {
            int col = n0 + wn + 16 * c + l15;
            float bv = bias[col];
#pragma unroll
            for (int i = 0; i < 4; i++) {
                int row = m0 + wm + 16 * r + lg * 4 + i;
                float v = acc[r][c][i] + bv;
                if (EPI == 0) {
                    v = v > 0.f ? v : 0.f;
                    C[(size_t)row * ldc + col] = f2bf(v);
                } else {
                    float e = eps[(size_t)row * 512 + col];
                    float enc = e * __expf(0.5f * v) + v;
                    C[(size_t)row * ldc + col] = f2bf(enc);
                }
            }
        }
    }
}

// ================= WHOLE-DECODER SINGLE KERNEL =============================
// 128 blocks x 1024 threads (16 waves). Block owns 16 batch rows COMPLETELY:
// h, xt, o live in LDS; all 128 steps run inside the kernel with only
// __syncthreads(). Gate weights (WB, 3MB) stream from L2 every step into
// registers as B-fragments (ping-pong prefetch); 16 blocks/XCD share the
// stream so WB stays L2-resident. No cross-block dataflow (no coherence
// hazard). Wave w owns unit-frags j={2w,2w+1} (r,z,n for units j*16..+15).
__global__ __launch_bounds__(1024, 1) void gru_all(
    const u16* __restrict__ encb, const u16* __restrict__ WB,
    const float* __restrict__ bih, const float* __restrict__ bhh,
    const u16* __restrict__ Wf1p, const float* __restrict__ bf1,
    const u16* __restrict__ Wf2p, const float* __restrict__ bf2,
    float* __restrict__ outp) {
    __shared__ __align__(16) u16 xtL[16 * 512];   // 16KB, XOR-swizzled
    __shared__ __align__(16) u16 hL[16 * 512];    // 16KB, XOR-swizzled (bf16 h)
    __shared__ __align__(16) float hfL[16 * 512]; // 32KB (f32 h)
    __shared__ __align__(16) u16 oL[16 * 64];     // 2KB, XOR-swizzled
    const int tid = threadIdx.x, lane = tid & 63, wave = tid >> 6;
    const int l15 = lane & 15, lg = lane >> 4;
    const int m0 = blockIdx.x * 16;
    const int sw = (l15 & 7) << 4;

    // ---- init: stage xt0 = encoded (pre-swizzled src), zero h, zero oL ----
    {
        int row = tid >> 6, slot = tid & 63;
        gload16((const char*)(encb + (size_t)(m0 + row) * 512) + ((slot ^ (row & 7)) * 16),
                (char*)xtL + tid * 16);
        u64* hz = (u64*)hL;
        hz[tid * 2] = 0ull;
        hz[tid * 2 + 1] = 0ull;
        u64* hfz = (u64*)hfL;
#pragma unroll
        for (int q = 0; q < 4; ++q) hfz[tid * 4 + q] = 0ull;
        if (tid < 256) ((u64*)oL)[tid] = 0ull;
    }
    // per-wave unit assignments + biases (regs for whole kernel)
    const int u0 = (2 * wave) * 16 + l15;
    const int u1 = (2 * wave + 1) * 16 + l15;
    const float br0 = bih[u0] + bhh[u0], bz0 = bih[512 + u0] + bhh[512 + u0];
    const float bgi0 = bih[1024 + u0], bgh0 = bhh[1024 + u0];
    const float br1 = bih[u1] + bhh[u1], bz1 = bih[512 + u1] + bhh[512 + u1];
    const float bgi1 = bih[1024 + u1], bgh1 = bhh[1024 + u1];
    const u16* bp[6];
    bp[0] = WB + (size_t)u0 * 1024 + lg * 8;           // r, j0
    bp[1] = WB + (size_t)u1 * 1024 + lg * 8;           // r, j1
    bp[2] = WB + (size_t)(512 + u0) * 1024 + lg * 8;   // z, j0
    bp[3] = WB + (size_t)(512 + u1) * 1024 + lg * 8;   // z, j1
    bp[4] = WB + (size_t)(1024 + u0) * 1024 + lg * 8;  // n, j0
    bp[5] = WB + (size_t)(1024 + u1) * 1024 + lg * 8;  // n, j1
    __syncthreads();

    for (int it = 0; it <= 128; ++it) {
        if (it > 0) {
            // ---- fc1(h_it) -> out[it-1] (+ oL) ----
            if (wave < 3) {
                f32x4 oa = (f32x4){0.f, 0.f, 0.f, 0.f};
                const u16* wb1 = Wf1p + (size_t)(16 * wave + l15) * 512 + lg * 8;
#pragma unroll
                for (int kf = 0; kf < 16; ++kf) {
                    bf16x8 a = *(const bf16x8*)((char*)hL + l15 * 1024 +
                                                ((kf * 64 + lg * 16) ^ sw));
                    oa = __builtin_amdgcn_mfma_f32_16x16x32_bf16(
                        a, *(const bf16x8*)(wb1 + kf * 32), oa, 0, 0, 0);
                }
                int col = 16 * wave + l15;
                float bv = (col < 42) ? bf1[col] : 0.f;
#pragma unroll
                for (int i = 0; i < 4; ++i) {
                    int row = lg * 4 + i;
                    float v = reluf_(oa[i] + bv);
                    if (col >= 42) v = 0.f;
                    int cb = col * 2;
                    *(u16*)((char*)oL + row * 128 +
                            (((cb & ~15) ^ ((row & 7) << 4)) | (cb & 15))) = f2bf(v);
                    if (col < 42)
                        outp[(size_t)(m0 + row) * 5376 + (size_t)(it - 1) * 42 + col] = v;
                }
            }
            if (it == 128) break;  // uniform exit after final fc1
            __syncthreads();       // oL ready
            // ---- fc2(oL) -> xtL (2 col-frags per wave) ----
            bf16x8 a2[2];
#pragma unroll
            for (int kf = 0; kf < 2; ++kf)
                a2[kf] = *(const bf16x8*)((char*)oL + l15 * 128 +
                                          ((kf * 64 + lg * 16) ^ sw));
#pragma unroll
            for (int ci = 0; ci < 2; ++ci) {
                int col = (2 * wave + ci) * 16 + l15;
                const u16* wb2 = Wf2p + (size_t)col * 64 + lg * 8;
                f32x4 xa = (f32x4){0.f, 0.f, 0.f, 0.f};
                xa = __builtin_amdgcn_mfma_f32_16x16x32_bf16(
                    a2[0], *(const bf16x8*)wb2, xa, 0, 0, 0);
                xa = __builtin_amdgcn_mfma_f32_16x16x32_bf16(
                    a2[1], *(const bf16x8*)(wb2 + 32), xa, 0, 0, 0);
                float bv = bf2[col];
                int cb = col * 2;
#pragma unroll
                for (int i = 0; i < 4; ++i) {
                    int row = lg * 4 + i;
                    float v = reluf_(xa[i] + bv);
                    *(u16*)((char*)xtL + row * 1024 +
                            (((cb & ~15) ^ ((row & 7) << 4)) | (cb & 15))) = f2bf(v);
                }
            }
            __syncthreads();  // xtL ready
        }

        // ---- gates: K=1024 over [xt(t<16) || h(t>=16)], ping-pong B ----
        f32x4 ar0 = (f32x4){0.f, 0.f, 0.f, 0.f};
        f32x4 ar1 = ar0, az0 = ar0, az1 = ar0, agi0 = ar0, agi1 = ar0,
              agh0 = ar0, agh1 = ar0;
        bf16x8 bA[6], bB[6];
#pragma unroll
        for (int q = 0; q < 6; ++q) bA[q] = *(const bf16x8*)(bp[q]);
#pragma unroll 2
        for (int t = 0; t < 16; t += 2) {
            bf16x8 a0 = *(const bf16x8*)((char*)xtL + l15 * 1024 +
                                         ((t * 64 + lg * 16) ^ sw));
#pragma unroll
            for (int q = 0; q < 6; ++q) bB[q] = *(const bf16x8*)(bp[q] + (t + 1) * 32);
            ar0 = __builtin_amdgcn_mfma_f32_16x16x32_bf16(a0, bA[0], ar0, 0, 0, 0);
            ar1 = __builtin_amdgcn_mfma_f32_16x16x32_bf16(a0, bA[1], ar1, 0, 0, 0);
            az0 = __builtin_amdgcn_mfma_f32_16x16x32_bf16(a0, bA[2], az0, 0, 0, 0);
            az1 = __builtin_amdgcn_mfma_f32_16x16x32_bf16(a0, bA[3], az1, 0, 0, 0);
            agi0 = __builtin_amdgcn_mfma_f32_16x16x32_bf16(a0, bA[4], agi0, 0, 0, 0);
            agi1 = __builtin_amdgcn_mfma_f32_16x16x32_bf16(a0, bA[5], agi1, 0, 0, 0);
            bf16x8 a1 = *(const bf16x8*)((char*)xtL + l15 * 1024 +
                                         (((t + 1) * 64 + lg * 16) ^ sw));
#pragma unroll
            for (int q = 0; q < 6; ++q) bA[q] = *(const bf16x8*)(bp[q] + (t + 2) * 32);
            ar0 = __builtin_amdgcn_mfma_f32_16x16x32_bf16(a1, bB[0], ar0, 0, 0, 0);
            ar1 = __builtin_amdgcn_mfma_f32_16x16x32_bf16(a1, bB[1], ar1, 0, 0, 0);
            az0 = __builtin_amdgcn_mfma_f32_16x16x32_bf16(a1, bB[2], az0, 0, 0, 0);
            az1 = __builtin_amdgcn_mfma_f32_16x16x32_bf16(a1, bB[3], az1, 0, 0, 0);
            agi0 = __builtin_amdgcn_mfma_f32_16x16x32_bf16(a1, bB[4], agi0, 0, 0, 0);
            agi1 = __builtin_amdgcn_mfma_f32_16x16x32_bf16(a1, bB[5], agi1, 0, 0, 0);
        }
#pragma unroll 2
        for (int t = 16; t < 32; t += 2) {
            bf16x8 a0 = *(const bf16x8*)((char*)hL + l15 * 1024 +
                                         (((t - 16) * 64 + lg * 16) ^ sw));
#pragma unroll
            for (int q = 0; q < 6; ++q) bB[q] = *(const bf16x8*)(bp[q] + (t + 1) * 32);
            ar0 = __builtin_amdgcn_mfma_f32_16x16x32_bf16(a0, bA[0], ar0, 0, 0, 0);
            ar1 = __builtin_amdgcn_mfma_f32_16x16x32_bf16(a0, bA[1], ar1, 0, 0, 0);
            az0 = __builtin_amdgcn_mfma_f32_16x16x32_bf16(a0, bA[2], az0, 0, 0, 0);
            az1 = __builtin_amdgcn_mfma_f32_16x16x32_bf16(a0, bA[3], az1, 0, 0, 0);
            agh0 = __builtin_amdgcn_mfma_f32_16x16x32_bf16(a0, bA[4], agh0, 0, 0, 0);
            agh1 = __builtin_amdgcn_mfma_f32_16x16x32_bf16(a0, bA[5], agh1, 0, 0, 0);
            bf16x8 a1 = *(const bf16x8*)((char*)hL + l15 * 1024 +
                                         (((t - 15) * 64 + lg * 16) ^ sw));
            int tn = (t + 2 < 32) ? (t + 2) : 0;  // avoid OOB on last prefetch
#pragma unroll
            for (int q = 0; q < 6; ++q) bA[q] = *(const bf16x8*)(bp[q] + tn * 32);
            ar0 = __builtin_amdgcn_mfma_f32_16x16x32_bf16(a1, bB[0], ar0, 0, 0, 0);
            ar1 = __builtin_amdgcn_mfma_f32_16x16x32_bf16(a1, bB[1], ar1, 0, 0, 0);
            az0 = __builtin_amdgcn_mfma_f32_16x16x32_bf16(a1, bB[2], az0, 0, 0, 0);
            az1 = __builtin_amdgcn_mfma_f32_16x16x32_bf16(a1, bB[3], az1, 0, 0, 0);
            agh0 = __builtin_amdgcn_mfma_f32_16x16x32_bf16(a1, bB[4], agh0, 0, 0, 0);
            agh1 = __builtin_amdgcn_mfma_f32_16x16x32_bf16(a1, bB[5], agh1, 0, 0, 0);
        }
        __syncthreads();  // all hL/xtL reads done before epilogue writes

        // ---- GRU update epilogue (this wave's 2 unit-frags) ----
#pragma unroll
        for (int i = 0; i < 4; ++i) {
            int row = lg * 4 + i;
            {
                float rv = sigmoidf_(ar0[i] + br0);
                float zv = sigmoidf_(az0[i] + bz0);
                float nv = tanhf_(agi0[i] + bgi0 + rv * (agh0[i] + bgh0));
                float hold = hfL[row * 512 + u0];
                float hn = (1.f - zv) * nv + zv * hold;
                hfL[row * 512 + u0] = hn;
                int cb = u0 * 2;
                *(u16*)((char*)hL + row * 1024 +
                        (((cb & ~15) ^ ((row & 7) << 4)) | (cb & 15))) = f2bf(hn);
            }
            {
                float rv = sigmoidf_(ar1[i] + br1);
                float zv = sigmoidf_(az1[i] + bz1);
                float nv = tanhf_(agi1[i] + bgi1 + rv * (agh1[i] + bgh1));
                float hold = hfL[row * 512 + u1];
                float hn = (1.f - zv) * nv + zv * hold;
                hfL[row * 512 + u1] = hn;
                int cb = u1 * 2;
                *(u16*)((char*)hL + row * 1024 +
                        (((cb & ~15) ^ ((row & 7) << 4)) | (cb & 15))) = f2bf(hn);
            }
        }
        __syncthreads();  // h_{it+1} ready for next fc1/gates
    }
}

// ---------------------------------------------------------------------------
extern "C" void kernel_launch(void* const* d_in, const int* in_sizes, int n_in,
                              void* d_out, int out_size, void* d_ws,
                              size_t ws_size, hipStream_t stream) {
    (void)in_sizes; (void)n_in; (void)out_size;
    const float* x = (const float*)d_in[0];
    const float* eps = (const float*)d_in[2];
    const float* We1 = (const float*)d_in[3];
    const float* be1 = (const float*)d_in[4];
    const float* We2 = (const float*)d_in[5];
    const float* be2 = (const float*)d_in[6];
    const float* We3 = (const float*)d_in[7];
    const float* be3 = (const float*)d_in[8];
    const float* We41 = (const float*)d_in[9];
    const float* be41 = (const float*)d_in[10];
    const float* Wih = (const float*)d_in[11];
    const float* bih = (const float*)d_in[12];
    const float* Whh = (const float*)d_in[13];
    const float* bhh = (const float*)d_in[14];
    const float* Wf1 = (const float*)d_in[15];
    const float* bf1 = (const float*)d_in[16];
    const float* Wf2 = (const float*)d_in[17];
    const float* bf2 = (const float*)d_in[18];
    float* out = (float*)d_out;

    char* ws = (char*)d_ws;
    size_t off = 0;
    auto alloc = [&](size_t bytes) -> char* {
        char* p = ws + off;
        off += (bytes + 255) & ~(size_t)255;
        return p;
    };
    u16* xb = (u16*)alloc(2048ull * 4864 * 2);
    u16* We1b = (u16*)alloc(2048ull * 4864 * 2);
    u16* We2b = (u16*)alloc(1024ull * 2048 * 2);
    u16* We3b = (u16*)alloc(512ull * 1024 * 2);
    u16* We41b = (u16*)alloc(512ull * 512 * 2);
    u16* WB = (u16*)alloc(1536ull * 1024 * 2);
    u16* h1b = (u16*)alloc(2048ull * 2048 * 2);
    u16* h2b = (u16*)alloc(2048ull * 1024 * 2);
    u16* h3b = (u16*)alloc(2048ull * 512 * 2);
    u16* encb = (u16*)alloc(2048ull * 512 * 2);
    u16* Wf1p = (u16*)alloc(48ull * 512 * 2);
    u16* Wf2p = (u16*)alloc(512ull * 64 * 2);
    if (off > ws_size) {
        fill_const<<<(11010048 + 255) / 256, 256, 0, stream>>>(out, 11010048, 54321.0f);
        return;
    }

    // 1 setup launch
    prep_all<<<8192, 256, 0, stream>>>(x, We1, We2, We3, We41, Wih, Whh, Wf1, Wf2,
                                       xb, We1b, We2b, We3b, We41b, WB, Wf1p, Wf2p);

    // encoder (bf16 MFMA), 4 launches
    gemm_bt<0><<<dim3(16, 16), 256, 0, stream>>>(xb, 4864, We1b, 4864, be1, h1b, 2048, 76, nullptr);
    gemm_bt<0><<<dim3(8, 16), 256, 0, stream>>>(h1b, 2048, We2b, 2048, be2, h2b, 1024, 32, nullptr);
    gemm_bt<0><<<dim3(4, 16), 256, 0, stream>>>(h2b, 1024, We3b, 1024, be3, h3b, 512, 16, nullptr);
    gemm_bt<1><<<dim3(4, 16), 256, 0, stream>>>(h3b, 512, We41b, 512, be41, encb, 512, 8, eps);

    // whole decoder: ONE launch (128 blocks x 16 rows, all 128 steps inside)
    gru_all<<<128, 1024, 0, stream>>>(encb, WB, bih, bhh, Wf1p, bf1, Wf2p, bf2, out);
}

// Round 14
// 9490.608 us; speedup vs baseline: 1.3838x; 1.3838x over previous
//
#include <hip/hip_runtime.h>
#include <hip/hip_bf16.h>
#include <cstdint>
#include <cstddef>

#define DEVI __device__ __forceinline__

typedef __attribute__((ext_vector_type(8))) short bf16x8;
typedef __attribute__((ext_vector_type(4))) float f32x4;
typedef unsigned short u16;
typedef unsigned int u32;
typedef unsigned long long u64;

DEVI u16 f2bf(float f) {
    u32 i = __builtin_bit_cast(u32, f);
    u32 r = (i + 0x7FFFu + ((i >> 16) & 1u)) >> 16;
    return (u16)r;
}
DEVI float sigmoidf_(float x) { return 1.0f / (1.0f + __expf(-x)); }
DEVI float tanhf_(float x) { return 2.0f / (1.0f + __expf(-2.0f * x)) - 1.0f; }
DEVI float reluf_(float x) { return x > 0.f ? x : 0.f; }

typedef const __attribute__((address_space(1))) void* gptr_t;
typedef __attribute__((address_space(3))) void* lptr_t;

DEVI void gload16(const void* g, void* l) {
    __builtin_amdgcn_global_load_lds((gptr_t)g, (lptr_t)l, 16, 0, 0);
}

__global__ void fill_const(float* __restrict__ p, int n, float v) {
    int i = blockIdx.x * 256 + threadIdx.x;
    if (i < n) p[i] = v;
}

// ---------------- fused setup: all f32->bf16 conversions in ONE launch -----
__global__ void prep_all(const float* __restrict__ x, const float* __restrict__ We1,
                         const float* __restrict__ We2, const float* __restrict__ We3,
                         const float* __restrict__ We41, const float* __restrict__ Wih,
                         const float* __restrict__ Whh, const float* __restrict__ Wf1,
                         const float* __restrict__ Wf2, u16* __restrict__ xb,
                         u16* __restrict__ We1b, u16* __restrict__ We2b,
                         u16* __restrict__ We3b, u16* __restrict__ We41b,
                         u16* __restrict__ WB, u16* __restrict__ Wf1p,
                         u16* __restrict__ Wf2p) {
    const long long T0 = 9961472, T1 = 19922944, T2 = 22020096, T3 = 22544384,
                    T4 = 22806528, T5 = 23592960, T6 = 24379392, T7 = 24403968,
                    T8 = 24436736;
    for (long long i = (long long)blockIdx.x * 256 + threadIdx.x; i < T8;
         i += (long long)gridDim.x * 256) {
        if (i < T1) {  // xb / We1b: [2048][4864] zero-padded from [2048][4860]
            long long j = (i < T0) ? i : i - T0;
            int r = (int)(j / 4864);
            int c = (int)(j - (long long)r * 4864);
            const float* s = (i < T0) ? x : We1;
            u16* d = (i < T0) ? xb : We1b;
            d[j] = (c < 4860) ? f2bf(s[(size_t)r * 4860 + c]) : (u16)0;
        } else if (i < T2) {
            int j = (int)(i - T1);
            We2b[j] = f2bf(We2[j]);
        } else if (i < T3) {
            int j = (int)(i - T2);
            We3b[j] = f2bf(We3[j]);
        } else if (i < T4) {
            int j = (int)(i - T3);
            We41b[j] = f2bf(We41[j]);
        } else if (i < T5) {  // WB[g][0:512] = Wih
            int j = (int)(i - T4);
            int g = j >> 9, k = j & 511;
            WB[(size_t)g * 1024 + k] = f2bf(Wih[j]);
        } else if (i < T6) {  // WB[g][512:1024] = Whh
            int j = (int)(i - T5);
            int g = j >> 9, k = j & 511;
            WB[(size_t)g * 1024 + 512 + k] = f2bf(Whh[j]);
        } else if (i < T7) {  // Wf1p [48][512], rows >=42 zero
            int j = (int)(i - T6);
            int r = j >> 9;
            Wf1p[j] = (r < 42) ? f2bf(Wf1[j]) : (u16)0;
        } else {  // Wf2p [512][64], k >= 42 zero
            int j = (int)(i - T7);
            int c = j >> 6, k = j & 63;
            Wf2p[j] = (k < 42) ? f2bf(Wf2[(size_t)c * 42 + k]) : (u16)0;
        }
    }
}

// ---------------- encoder GEMM: C = epi(A @ B^T + bias) (validated) --------
template <int EPI>
__global__ __launch_bounds__(256) void gemm_bt(
    const u16* __restrict__ A, int lda, const u16* __restrict__ B, int ldb,
    const float* __restrict__ bias, u16* __restrict__ C, int ldc, int ktiles,
    const float* __restrict__ eps) {
    __shared__ u16 As[128 * 64];
    __shared__ u16 Bs[128 * 64];
    const int tid = threadIdx.x;
    const int lane = tid & 63;
    const int wave = tid >> 6;
    const int m0 = blockIdx.y * 128;
    const int n0 = blockIdx.x * 128;
    const int l15 = lane & 15, lg = lane >> 4;
    const int wm = (wave >> 1) * 64, wn = (wave & 1) * 64;

    f32x4 acc[4][4];
#pragma unroll
    for (int r = 0; r < 4; r++)
#pragma unroll
        for (int c = 0; c < 4; c++) acc[r][c] = (f32x4){0.f, 0.f, 0.f, 0.f};

    for (int t = 0; t < ktiles; ++t) {
        const int k0 = t * 64;
#pragma unroll
        for (int q = 0; q < 4; ++q) {
            int chunk = q * 4 + wave;
            int o = chunk * 1024 + lane * 16;
            int row = o >> 7;
            int cb = o & 127;
            gload16((const char*)(A + (size_t)(m0 + row) * lda + k0) + cb,
                    (char*)As + chunk * 1024);
            gload16((const char*)(B + (size_t)(n0 + row) * ldb + k0) + cb,
                    (char*)Bs + chunk * 1024);
        }
        __syncthreads();
#pragma unroll
        for (int kf = 0; kf < 2; ++kf) {
            bf16x8 a[4], b[4];
#pragma unroll
            for (int r = 0; r < 4; r++)
                a[r] = *(const bf16x8*)&As[(wm + 16 * r + l15) * 64 + kf * 32 + lg * 8];
#pragma unroll
            for (int c = 0; c < 4; c++)
                b[c] = *(const bf16x8*)&Bs[(wn + 16 * c + l15) * 64 + kf * 32 + lg * 8];
#pragma unroll
            for (int r = 0; r < 4; r++)
#pragma unroll
                for (int c = 0; c < 4; c++)
                    acc[r][c] = __builtin_amdgcn_mfma_f32_16x16x32_bf16(
                        a[r], b[c], acc[r][c], 0, 0, 0);
        }
        __syncthreads();
    }
#pragma unroll
    for (int r = 0; r < 4; r++) {
#pragma unroll
        for (int c = 0; c < 4; c++) {
            int col = n0 + wn + 16 * c + l15;
            float bv = bias[col];
#pragma unroll
            for (int i = 0; i < 4; i++) {
                int row = m0 + wm + 16 * r + lg * 4 + i;
                float v = acc[r][c][i] + bv;
                if (EPI == 0) {
                    v = v > 0.f ? v : 0.f;
                    C[(size_t)row * ldc + col] = f2bf(v);
                } else {
                    float e = eps[(size_t)row * 512 + col];
                    float enc = e * __expf(0.5f * v) + v;
                    C[(size_t)row * ldc + col] = f2bf(enc);
                }
            }
        }
    }
}

// ================= FUSED PER-STEP DECODER (no B-staging) ===================
// Linear grid 256; sb = bid&7 (XCD-resident WB slice), rb = bid>>3.
// Block: 64 rows (m0) x 64 units (S). Wave (wr=wave>>2, wu=wave&3):
// 16 rows x 16 units. Gate weights read PER-LANE from global (L2) with
// 1-ahead register prefetch — NO LDS staging, NO barriers in the K-loop.
// Only 3 barriers per step (init/oL/xtL). LDS 72KB -> 2 blocks/CU.
// MODE 0: stage xt=enc into LDS; gates only.
// MODE 1: fc1(h)->out+oL; fc2(oL)->xtL; gates(xtL,h)->h'.
// MODE 2: fc1(h)->out only (32 blocks).
template <int MODE>
__global__ __launch_bounds__(1024, 2) void gru_step(
    const u16* __restrict__ xt0, const u16* __restrict__ hbR,
    const float* __restrict__ hfR, u16* __restrict__ hbW,
    float* __restrict__ hfW, const u16* __restrict__ WB,
    const float* __restrict__ bih, const float* __restrict__ bhh,
    const u16* __restrict__ Wf1p, const float* __restrict__ bf1,
    const u16* __restrict__ Wf2p, const float* __restrict__ bf2,
    float* __restrict__ outp, int sidx) {
    __shared__ __align__(16) u16 xtL[64 * 512];  // 64KB swizzled xt tile
    __shared__ __align__(16) u16 oL[64 * 64];    // 8KB fc1-out tile
    const int tid = threadIdx.x, lane = tid & 63, wave = tid >> 6;
    const int wr = wave >> 2, wu = wave & 3;
    const int l15 = lane & 15, lg = lane >> 4;
    const int bid = blockIdx.x;
    const int sb = (MODE == 2) ? 0 : (bid & 7);
    const int rb = (MODE == 2) ? bid : (bid >> 3);
    const int S = sb * 64, m0 = rb * 64;
    const int sw = (l15 & 7) << 4;

    if (MODE == 0) {
        // stage xtL from encoded: 4096 16B issues, src slot pre-swizzled
#pragma unroll
        for (int k2 = 0; k2 < 4; ++k2) {
            int j = tid + k2 * 1024;
            int row = j >> 6, slot = j & 63;
            gload16((const char*)(xt0 + (size_t)(m0 + row) * 512) + (slot ^ (row & 7)) * 16,
                    (char*)xtL + j * 16);
        }
        __syncthreads();
    }

    if (MODE >= 1) {
        if (MODE == 1) {
            ((u64*)oL)[tid] = 0ull;  // zero incl. pad cols 48..63
            __syncthreads();
        }
        // ---- fc1: 16 rows x 16 cols per wave (wu<3) ----
        if (wu < 3) {
            f32x4 oa = (f32x4){0.f, 0.f, 0.f, 0.f};
            const u16* ha = hbR + (size_t)(m0 + 16 * wr + l15) * 512 + lg * 8;
            const u16* wb1 = Wf1p + (size_t)(16 * wu + l15) * 512 + lg * 8;
#pragma unroll
            for (int kf = 0; kf < 16; ++kf) {
                bf16x8 a = *(const bf16x8*)(ha + kf * 32);
                bf16x8 b = *(const bf16x8*)(wb1 + kf * 32);
                oa = __builtin_amdgcn_mfma_f32_16x16x32_bf16(a, b, oa, 0, 0, 0);
            }
            int col = 16 * wu + l15;
            float bv = (col < 42) ? bf1[col] : 0.f;
#pragma unroll
            for (int i = 0; i < 4; ++i) {
                int row = 16 * wr + lg * 4 + i;
                float v = reluf_(oa[i] + bv);
                if (col >= 42) v = 0.f;
                if (MODE == 1) {
                    int cb = col * 2;
                    *(u16*)((char*)oL + row * 128 +
                            (((cb & ~15) ^ ((row & 7) << 4)) | (cb & 15))) = f2bf(v);
                }
                if (sb == 0 && col < 42)
                    outp[(size_t)(m0 + row) * 5376 + (size_t)sidx * 42 + col] = v;
            }
        }
    }

    if (MODE == 1) {
        __syncthreads();  // oL complete
        // ---- fc2: 16 rows x 128 cols per wave -> xtL ----
        bf16x8 a2[2];
#pragma unroll
        for (int kf = 0; kf < 2; ++kf) {
            int row = 16 * wr + l15;
            a2[kf] = *(const bf16x8*)((char*)oL + row * 128 +
                                      ((kf * 64 + lg * 16) ^ ((row & 7) << 4)));
        }
#pragma unroll
        for (int ci = 0; ci < 8; ++ci) {
            int col = 128 * wu + 16 * ci + l15;
            const u16* wb2 = Wf2p + (size_t)col * 64 + lg * 8;
            f32x4 xa = (f32x4){0.f, 0.f, 0.f, 0.f};
            xa = __builtin_amdgcn_mfma_f32_16x16x32_bf16(a2[0], *(const bf16x8*)wb2, xa, 0, 0, 0);
            xa = __builtin_amdgcn_mfma_f32_16x16x32_bf16(a2[1], *(const bf16x8*)(wb2 + 32), xa, 0, 0, 0);
            float bv = bf2[col];
            int cb = col * 2;
#pragma unroll
            for (int i = 0; i < 4; ++i) {
                int row = 16 * wr + lg * 4 + i;
                float v = reluf_(xa[i] + bv);
                *(u16*)((char*)xtL + row * 1024 +
                        (((cb & ~15) ^ ((row & 7) << 4)) | (cb & 15))) = f2bf(v);
            }
        }
        __syncthreads();  // xtL ready
    }

    if (MODE <= 1) {
        // ---- gates: K=1024 over [xt(t<16) || h(t>=16)]; B per-lane from L2,
        //      1-ahead register prefetch; ZERO barriers in this loop ----
        f32x4 ar = (f32x4){0.f, 0.f, 0.f, 0.f};
        f32x4 az = ar, agi = ar, agh = ar;
        const u16* bpr = WB + (size_t)(S + wu * 16 + l15) * 1024 + lg * 8;
        const u16* bpz = bpr + 512 * 1024;
        const u16* bpn = bpz + 512 * 1024;
        const int arow = 16 * wr + l15;
        const u16* hA = hbR + (size_t)(m0 + arow) * 512 + lg * 8;
        bf16x8 brA = *(const bf16x8*)(bpr);
        bf16x8 bzA = *(const bf16x8*)(bpz);
        bf16x8 bnA = *(const bf16x8*)(bpn);
        bf16x8 brB, bzB, bnB;
#pragma unroll 4
        for (int t = 0; t < 32; ++t) {
            if (t < 31) {
                brB = *(const bf16x8*)(bpr + (t + 1) * 32);
                bzB = *(const bf16x8*)(bpz + (t + 1) * 32);
                bnB = *(const bf16x8*)(bpn + (t + 1) * 32);
            }
            bf16x8 a;
            if (t < 16)
                a = *(const bf16x8*)((char*)xtL + arow * 1024 + ((t * 64 + lg * 16) ^ sw));
            else
                a = *(const bf16x8*)(hA + (t - 16) * 32);
            ar = __builtin_amdgcn_mfma_f32_16x16x32_bf16(a, brA, ar, 0, 0, 0);
            az = __builtin_amdgcn_mfma_f32_16x16x32_bf16(a, bzA, az, 0, 0, 0);
            if (t < 16)
                agi = __builtin_amdgcn_mfma_f32_16x16x32_bf16(a, bnA, agi, 0, 0, 0);
            else
                agh = __builtin_amdgcn_mfma_f32_16x16x32_bf16(a, bnA, agh, 0, 0, 0);
            brA = brB;
            bzA = bzB;
            bnA = bnB;
        }
        // ---- GRU update epilogue ----
        int hu = S + 16 * wu + l15;
        float br_ = bih[hu] + bhh[hu];
        float bz_ = bih[512 + hu] + bhh[512 + hu];
        float bgi = bih[1024 + hu];
        float bgh = bhh[1024 + hu];
#pragma unroll
        for (int i = 0; i < 4; ++i) {
            int row = m0 + 16 * wr + lg * 4 + i;
            float rv = sigmoidf_(ar[i] + br_);
            float zv = sigmoidf_(az[i] + bz_);
            float nv = tanhf_(agi[i] + bgi + rv * (agh[i] + bgh));
            float hold = hfR[(size_t)row * 512 + hu];
            float hn = (1.f - zv) * nv + zv * hold;
            hfW[(size_t)row * 512 + hu] = hn;
            hbW[(size_t)row * 512 + hu] = f2bf(hn);
        }
    }
}

// ---------------------------------------------------------------------------
extern "C" void kernel_launch(void* const* d_in, const int* in_sizes, int n_in,
                              void* d_out, int out_size, void* d_ws,
                              size_t ws_size, hipStream_t stream) {
    (void)in_sizes; (void)n_in; (void)out_size;
    const float* x = (const float*)d_in[0];
    const float* eps = (const float*)d_in[2];
    const float* We1 = (const float*)d_in[3];
    const float* be1 = (const float*)d_in[4];
    const float* We2 = (const float*)d_in[5];
    const float* be2 = (const float*)d_in[6];
    const float* We3 = (const float*)d_in[7];
    const float* be3 = (const float*)d_in[8];
    const float* We41 = (const float*)d_in[9];
    const float* be41 = (const float*)d_in[10];
    const float* Wih = (const float*)d_in[11];
    const float* bih = (const float*)d_in[12];
    const float* Whh = (const float*)d_in[13];
    const float* bhh = (const float*)d_in[14];
    const float* Wf1 = (const float*)d_in[15];
    const float* bf1 = (const float*)d_in[16];
    const float* Wf2 = (const float*)d_in[17];
    const float* bf2 = (const float*)d_in[18];
    float* out = (float*)d_out;

    char* ws = (char*)d_ws;
    size_t off = 0;
    auto alloc = [&](size_t bytes) -> char* {
        char* p = ws + off;
        off += (bytes + 255) & ~(size_t)255;
        return p;
    };
    u16* xb = (u16*)alloc(2048ull * 4864 * 2);
    u16* We1b = (u16*)alloc(2048ull * 4864 * 2);
    u16* We2b = (u16*)alloc(1024ull * 2048 * 2);
    u16* We3b = (u16*)alloc(512ull * 1024 * 2);
    u16* We41b = (u16*)alloc(512ull * 512 * 2);
    u16* WB = (u16*)alloc(1536ull * 1024 * 2);
    u16* h1b = (u16*)alloc(2048ull * 2048 * 2);
    u16* h2b = (u16*)alloc(2048ull * 1024 * 2);
    u16* h3b = (u16*)alloc(2048ull * 512 * 2);
    u16* encb = (u16*)alloc(2048ull * 512 * 2);
    u16* hb0 = (u16*)alloc(2048ull * 512 * 2);
    u16* hb1 = (u16*)alloc(2048ull * 512 * 2);
    float* hf0 = (float*)alloc(2048ull * 512 * 4);
    float* hf1 = (float*)alloc(2048ull * 512 * 4);
    u16* Wf1p = (u16*)alloc(48ull * 512 * 2);
    u16* Wf2p = (u16*)alloc(512ull * 64 * 2);
    if (off > ws_size) {
        fill_const<<<(11010048 + 255) / 256, 256, 0, stream>>>(out, 11010048, 54321.0f);
        return;
    }
    u16* hb[2] = {hb0, hb1};
    float* hfl[2] = {hf0, hf1};

    // 1 setup launch + h init
    prep_all<<<8192, 256, 0, stream>>>(x, We1, We2, We3, We41, Wih, Whh, Wf1, Wf2,
                                       xb, We1b, We2b, We3b, We41b, WB, Wf1p, Wf2p);
    hipMemsetAsync(hb0, 0, 2048ull * 512 * 2, stream);
    hipMemsetAsync(hf0, 0, 2048ull * 512 * 4, stream);

    // encoder (bf16 MFMA), 4 launches
    gemm_bt<0><<<dim3(16, 16), 256, 0, stream>>>(xb, 4864, We1b, 4864, be1, h1b, 2048, 76, nullptr);
    gemm_bt<0><<<dim3(8, 16), 256, 0, stream>>>(h1b, 2048, We2b, 2048, be2, h2b, 1024, 32, nullptr);
    gemm_bt<0><<<dim3(4, 16), 256, 0, stream>>>(h2b, 1024, We3b, 1024, be3, h3b, 512, 16, nullptr);
    gemm_bt<1><<<dim3(4, 16), 256, 0, stream>>>(h3b, 512, We41b, 512, be41, encb, 512, 8, eps);

    // decoder: one fused kernel per step (XCD-swizzled, no B staging)
    gru_step<0><<<256, 1024, 0, stream>>>(encb, hb0, hf0, hb1, hf1, WB, bih,
                                          bhh, Wf1p, bf1, Wf2p, bf2, out, 0);
    for (int i = 1; i < 128; ++i) {
        int p = i & 1;
        gru_step<1><<<256, 1024, 0, stream>>>(nullptr, hb[p], hfl[p],
                                              hb[p ^ 1], hfl[p ^ 1], WB, bih,
                                              bhh, Wf1p, bf1, Wf2p, bf2, out,
                                              i - 1);
    }
    gru_step<2><<<32, 1024, 0, stream>>>(nullptr, hb0, hf0, nullptr, nullptr,
                                         WB, bih, bhh, Wf1p, bf1, Wf2p, bf2,
                                         out, 127);
}

// Round 15
// 4843.852 us; speedup vs baseline: 2.7112x; 1.9593x over previous
//
#include <hip/hip_runtime.h>
#include <hip/hip_bf16.h>
#include <cstdint>
#include <cstddef>

#define DEVI __device__ __forceinline__

typedef __attribute__((ext_vector_type(8))) short bf16x8;
typedef __attribute__((ext_vector_type(4))) float f32x4;
typedef unsigned short u16;
typedef unsigned int u32;
typedef unsigned long long u64;

DEVI u16 f2bf(float f) {
    u32 i = __builtin_bit_cast(u32, f);
    u32 r = (i + 0x7FFFu + ((i >> 16) & 1u)) >> 16;
    return (u16)r;
}
DEVI float sigmoidf_(float x) { return 1.0f / (1.0f + __expf(-x)); }
DEVI float tanhf_(float x) { return 2.0f / (1.0f + __expf(-2.0f * x)) - 1.0f; }
DEVI float reluf_(float x) { return x > 0.f ? x : 0.f; }

typedef const __attribute__((address_space(1))) void* gptr_t;
typedef __attribute__((address_space(3))) void* lptr_t;

DEVI void gload16(const void* g, void* l) {
    __builtin_amdgcn_global_load_lds((gptr_t)g, (lptr_t)l, 16, 0, 0);
}

__global__ void fill_const(float* __restrict__ p, int n, float v) {
    int i = blockIdx.x * 256 + threadIdx.x;
    if (i < n) p[i] = v;
}

// ---------------- fused setup: all f32->bf16 conversions in ONE launch -----
__global__ void prep_all(const float* __restrict__ x, const float* __restrict__ We1,
                         const float* __restrict__ We2, const float* __restrict__ We3,
                         const float* __restrict__ We41, const float* __restrict__ Wih,
                         const float* __restrict__ Whh, const float* __restrict__ Wf1,
                         const float* __restrict__ Wf2, u16* __restrict__ xb,
                         u16* __restrict__ We1b, u16* __restrict__ We2b,
                         u16* __restrict__ We3b, u16* __restrict__ We41b,
                         u16* __restrict__ WB, u16* __restrict__ Wf1p,
                         u16* __restrict__ Wf2p) {
    const long long T0 = 9961472, T1 = 19922944, T2 = 22020096, T3 = 22544384,
                    T4 = 22806528, T5 = 23592960, T6 = 24379392, T7 = 24403968,
                    T8 = 24436736;
    for (long long i = (long long)blockIdx.x * 256 + threadIdx.x; i < T8;
         i += (long long)gridDim.x * 256) {
        if (i < T1) {  // xb / We1b: [2048][4864] zero-padded from [2048][4860]
            long long j = (i < T0) ? i : i - T0;
            int r = (int)(j / 4864);
            int c = (int)(j - (long long)r * 4864);
            const float* s = (i < T0) ? x : We1;
            u16* d = (i < T0) ? xb : We1b;
            d[j] = (c < 4860) ? f2bf(s[(size_t)r * 4860 + c]) : (u16)0;
        } else if (i < T2) {
            int j = (int)(i - T1);
            We2b[j] = f2bf(We2[j]);
        } else if (i < T3) {
            int j = (int)(i - T2);
            We3b[j] = f2bf(We3[j]);
        } else if (i < T4) {
            int j = (int)(i - T3);
            We41b[j] = f2bf(We41[j]);
        } else if (i < T5) {  // WB[g][0:512] = Wih
            int j = (int)(i - T4);
            int g = j >> 9, k = j & 511;
            WB[(size_t)g * 1024 + k] = f2bf(Wih[j]);
        } else if (i < T6) {  // WB[g][512:1024] = Whh
            int j = (int)(i - T5);
            int g = j >> 9, k = j & 511;
            WB[(size_t)g * 1024 + 512 + k] = f2bf(Whh[j]);
        } else if (i < T7) {  // Wf1p [48][512], rows >=42 zero
            int j = (int)(i - T6);
            int r = j >> 9;
            Wf1p[j] = (r < 42) ? f2bf(Wf1[j]) : (u16)0;
        } else {  // Wf2p [512][64], k >= 42 zero
            int j = (int)(i - T7);
            int c = j >> 6, k = j & 63;
            Wf2p[j] = (k < 42) ? f2bf(Wf2[(size_t)c * 42 + k]) : (u16)0;
        }
    }
}

// ---------------- encoder GEMM: C = epi(A @ B^T + bias) (validated) --------
template <int EPI>
__global__ __launch_bounds__(256) void gemm_bt(
    const u16* __restrict__ A, int lda, const u16* __restrict__ B, int ldb,
    const float* __restrict__ bias, u16* __restrict__ C, int ldc, int ktiles,
    const float* __restrict__ eps) {
    __shared__ u16 As[128 * 64];
    __shared__ u16 Bs[128 * 64];
    const int tid = threadIdx.x;
    const int lane = tid & 63;
    const int wave = tid >> 6;
    const int m0 = blockIdx.y * 128;
    const int n0 = blockIdx.x * 128;
    const int l15 = lane & 15, lg = lane >> 4;
    const int wm = (wave >> 1) * 64, wn = (wave & 1) * 64;

    f32x4 acc[4][4];
#pragma unroll
    for (int r = 0; r < 4; r++)
#pragma unroll
        for (int c = 0; c < 4; c++) acc[r][c] = (f32x4){0.f, 0.f, 0.f, 0.f};

    for (int t = 0; t < ktiles; ++t) {
        const int k0 = t * 64;
#pragma unroll
        for (int q = 0; q < 4; ++q) {
            int chunk = q * 4 + wave;
            int o = chunk * 1024 + lane * 16;
            int row = o >> 7;
            int cb = o & 127;
            gload16((const char*)(A + (size_t)(m0 + row) * lda + k0) + cb,
                    (char*)As + chunk * 1024);
            gload16((const char*)(B + (size_t)(n0 + row) * ldb + k0) + cb,
                    (char*)Bs + chunk * 1024);
        }
        __syncthreads();
#pragma unroll
        for (int kf = 0; kf < 2; ++kf) {
            bf16x8 a[4], b[4];
#pragma unroll
            for (int r = 0; r < 4; r++)
                a[r] = *(const bf16x8*)&As[(wm + 16 * r + l15) * 64 + kf * 32 + lg * 8];
#pragma unroll
            for (int c = 0; c < 4; c++)
                b[c] = *(const bf16x8*)&Bs[(wn + 16 * c + l15) * 64 + kf * 32 + lg * 8];
#pragma unroll
            for (int r = 0; r < 4; r++)
#pragma unroll
                for (int c = 0; c < 4; c++)
                    acc[r][c] = __builtin_amdgcn_mfma_f32_16x16x32_bf16(
                        a[r], b[c], acc[r][c], 0, 0, 0);
        }
        __syncthreads();
    }
#pragma unroll
    for (int r = 0; r < 4; r++) {
#pragma unroll
        for (int c = 0; c < 4; c++) {
            int col = n0 + wn + 16 * c + l15;
            float bv = bias[col];
#pragma unroll
            for (int i = 0; i < 4; i++) {
                int row = m0 + wm + 16 * r + lg * 4 + i;
                float v = acc[r][c][i] + bv;
                if (EPI == 0) {
                    v = v > 0.f ? v : 0.f;
                    C[(size_t)row * ldc + col] = f2bf(v);
                } else {
                    float e = eps[(size_t)row * 512 + col];
                    float enc = e * __expf(0.5f * v) + v;
                    C[(size_t)row * ldc + col] = f2bf(enc);
                }
            }
        }
    }
}

// ================= FUSED PER-STEP DECODER (counted-vmcnt pipeline) =========
// Linear grid 256; sb = bid&7 (XCD-resident WB slice), rb = bid>>3.
// Block: 64 rows x 64 units; wave (wr,wu): 16 rows x 16 units.
// Gates loop uses T3/T4: stage(t+1) stays IN FLIGHT across a raw s_barrier;
// counted s_waitcnt vmcnt(N) waits only for stage(t). Barrier at iter END
// preserves R11/R12's buffer-parity safety (no write-during-read).
// Wave-uniform issue counts: waves 0-7 stage 2 chunks, waves 8-15 stage 1.
template <int MODE>
__global__ __launch_bounds__(1024, 1) void gru_step(
    const u16* __restrict__ xt0, const u16* __restrict__ hbR,
    const float* __restrict__ hfR, u16* __restrict__ hbW,
    float* __restrict__ hfW, const u16* __restrict__ WB,
    const float* __restrict__ bih, const float* __restrict__ bhh,
    const u16* __restrict__ Wf1p, const float* __restrict__ bf1,
    const u16* __restrict__ Wf2p, const float* __restrict__ bf2,
    float* __restrict__ outp, int sidx) {
    __shared__ __align__(16) u16 xtL[64 * 512];     // 64KB swizzled xt tile
    __shared__ __align__(16) u16 Bst[2][192 * 64];  // 2x24KB gate-W dbuf
    __shared__ __align__(16) u16 oL[64 * 64];       // 8KB fc1-out tile
    const int tid = threadIdx.x, lane = tid & 63, wave = tid >> 6;
    const int wr = wave >> 2, wu = wave & 3;
    const int l15 = lane & 15, lg = lane >> 4;
    const int bid = blockIdx.x;
    const int sb = (MODE == 2) ? 0 : (bid & 7);
    const int rb = (MODE == 2) ? bid : (bid >> 3);
    const int S = sb * 64, m0 = rb * 64;
    const int sw = (l15 & 7) << 4;

    if (MODE == 0) {
        // stage xtL from encoded: 4096 16B issues, src slot pre-swizzled
#pragma unroll
        for (int k2 = 0; k2 < 4; ++k2) {
            int j = tid + k2 * 1024;
            int row = j >> 6, slot = j & 63;
            gload16((const char*)(xt0 + (size_t)(m0 + row) * 512) + (slot ^ (row & 7)) * 16,
                    (char*)xtL + j * 16);
        }
    }

    if (MODE >= 1) {
        if (MODE == 1) {
            ((u64*)oL)[tid] = 0ull;  // zero incl. pad cols 48..63
            __syncthreads();
        }
        // ---- fc1: 16 rows x 16 cols per wave (wu<3) ----
        if (wu < 3) {
            f32x4 oa = (f32x4){0.f, 0.f, 0.f, 0.f};
            const u16* ha = hbR + (size_t)(m0 + 16 * wr + l15) * 512 + lg * 8;
            const u16* wb1 = Wf1p + (size_t)(16 * wu + l15) * 512 + lg * 8;
#pragma unroll
            for (int kf = 0; kf < 16; ++kf) {
                bf16x8 a = *(const bf16x8*)(ha + kf * 32);
                bf16x8 b = *(const bf16x8*)(wb1 + kf * 32);
                oa = __builtin_amdgcn_mfma_f32_16x16x32_bf16(a, b, oa, 0, 0, 0);
            }
            int col = 16 * wu + l15;
            float bv = (col < 42) ? bf1[col] : 0.f;
#pragma unroll
            for (int i = 0; i < 4; ++i) {
                int row = 16 * wr + lg * 4 + i;
                float v = reluf_(oa[i] + bv);
                if (col >= 42) v = 0.f;
                if (MODE == 1) {
                    int cb = col * 2;
                    *(u16*)((char*)oL + row * 128 +
                            (((cb & ~15) ^ ((row & 7) << 4)) | (cb & 15))) = f2bf(v);
                }
                if (sb == 0 && col < 42)
                    outp[(size_t)(m0 + row) * 5376 + (size_t)sidx * 42 + col] = v;
            }
        }
    }

    if (MODE == 1) {
        __syncthreads();  // oL complete
        // ---- fc2: 16 rows x 128 cols per wave -> xtL ----
        bf16x8 a2[2];
#pragma unroll
        for (int kf = 0; kf < 2; ++kf) {
            int row = 16 * wr + l15;
            a2[kf] = *(const bf16x8*)((char*)oL + row * 128 +
                                      ((kf * 64 + lg * 16) ^ ((row & 7) << 4)));
        }
#pragma unroll
        for (int ci = 0; ci < 8; ++ci) {
            int col = 128 * wu + 16 * ci + l15;
            const u16* wb2 = Wf2p + (size_t)col * 64 + lg * 8;
            f32x4 xa = (f32x4){0.f, 0.f, 0.f, 0.f};
            xa = __builtin_amdgcn_mfma_f32_16x16x32_bf16(a2[0], *(const bf16x8*)wb2, xa, 0, 0, 0);
            xa = __builtin_amdgcn_mfma_f32_16x16x32_bf16(a2[1], *(const bf16x8*)(wb2 + 32), xa, 0, 0, 0);
            float bv = bf2[col];
            int cb = col * 2;
#pragma unroll
            for (int i = 0; i < 4; ++i) {
                int row = 16 * wr + lg * 4 + i;
                float v = reluf_(xa[i] + bv);
                *(u16*)((char*)xtL + row * 1024 +
                        (((cb & ~15) ^ ((row & 7) << 4)) | (cb & 15))) = f2bf(v);
            }
        }
    }

    if (MODE <= 1) {
        __syncthreads();  // xtL ready (MODE0 stage drain or fc2 ds_writes)

        // ---- gates: r,z over [xt||h]; gi_n (t<8), gh_n (t>=8) ----
        auto stageB = [&](int buf, int t) {
            {
                int j = tid;
                int row = j >> 3, slot = j & 7;
                int gate = row >> 6, unit = row & 63;
                gload16(WB + (size_t)(gate * 512 + S + unit) * 1024 + t * 64 +
                            (slot ^ (row & 7)) * 8,
                        (char*)Bst + buf * 24576 + j * 16);
            }
            if (tid < 512) {  // waves 0-7 only (wave-uniform)
                int j = tid + 1024;
                int row = j >> 3, slot = j & 7;
                int gate = row >> 6, unit = row & 63;
                gload16(WB + (size_t)(gate * 512 + S + unit) * 1024 + t * 64 +
                            (slot ^ (row & 7)) * 8,
                        (char*)Bst + buf * 24576 + j * 16);
            }
        };
        f32x4 ar = (f32x4){0.f, 0.f, 0.f, 0.f};
        f32x4 az = ar, agi = ar, agh = ar;
        const int arow = 16 * wr + l15;
        const u16* hrow = hbR + (size_t)(m0 + arow) * 512 + lg * 8;
        bf16x8 hc0, hc1, hp0, hp1;

        stageB(0, 0);
        for (int t = 0; t < 16; ++t) {
            // issue h-prefetch for t+1 (2 vmem ops/wave, t in [7,14])
            if (t >= 7 && t < 15) {
                const u16* hs = hrow + (t - 7) * 64;
                hp0 = *(const bf16x8*)hs;
                hp1 = *(const bf16x8*)(hs + 32);
            }
            // issue next B-stage (waves 0-7: 2 ops; waves 8-15: 1 op)
            if (t < 15) stageB((t + 1) & 1, t + 1);
            __builtin_amdgcn_sched_barrier(0);
            // counted wait: only stage(t) (+older) must complete; stage(t+1)
            // and hp(t+1) stay in flight across the barrier (T4).
            if (t == 15) {
                asm volatile("s_waitcnt vmcnt(0)");
            } else if (t >= 7) {
                if (wave < 8) asm volatile("s_waitcnt vmcnt(4)");
                else          asm volatile("s_waitcnt vmcnt(3)");
            } else {
                if (wave < 8) asm volatile("s_waitcnt vmcnt(2)");
                else          asm volatile("s_waitcnt vmcnt(1)");
            }
            __builtin_amdgcn_sched_barrier(0);
            __builtin_amdgcn_s_barrier();  // raw: all waves' stage(t) landed
            __builtin_amdgcn_sched_barrier(0);

            bf16x8 a[2];
            if (t < 8) {
#pragma unroll
                for (int kf = 0; kf < 2; ++kf)
                    a[kf] = *(const bf16x8*)((char*)xtL + arow * 1024 +
                                             ((t * 128 + kf * 64 + lg * 16) ^ sw));
            } else {
                a[0] = hc0;
                a[1] = hc1;
            }
            const char* bb = (const char*)Bst + (t & 1) * 24576;
            int rb0 = 16 * wu + l15;
            int swb = (rb0 & 7) << 4;
#pragma unroll
            for (int kf = 0; kf < 2; ++kf) {
                int kb = kf * 64 + lg * 16;
                bf16x8 br = *(const bf16x8*)(bb + (size_t)rb0 * 128 + (kb ^ swb));
                bf16x8 bz = *(const bf16x8*)(bb + (size_t)(64 + rb0) * 128 + (kb ^ swb));
                bf16x8 bn = *(const bf16x8*)(bb + (size_t)(128 + rb0) * 128 + (kb ^ swb));
                ar = __builtin_amdgcn_mfma_f32_16x16x32_bf16(a[kf], br, ar, 0, 0, 0);
                az = __builtin_amdgcn_mfma_f32_16x16x32_bf16(a[kf], bz, az, 0, 0, 0);
                if (t < 8)
                    agi = __builtin_amdgcn_mfma_f32_16x16x32_bf16(a[kf], bn, agi, 0, 0, 0);
                else
                    agh = __builtin_amdgcn_mfma_f32_16x16x32_bf16(a[kf], bn, agh, 0, 0, 0);
            }
            hc0 = hp0;
            hc1 = hp1;
            __builtin_amdgcn_sched_barrier(0);
            // end-of-iter raw barrier: no wave may start overwriting buf
            // (t+2 parity == t parity) until ALL waves finished reading buf(t).
            __builtin_amdgcn_s_barrier();
        }
        // ---- GRU update epilogue ----
        int hu = S + 16 * wu + l15;
        float br_ = bih[hu] + bhh[hu];
        float bz_ = bih[512 + hu] + bhh[512 + hu];
        float bgi = bih[1024 + hu];
        float bgh = bhh[1024 + hu];
#pragma unroll
        for (int i = 0; i < 4; ++i) {
            int row = m0 + 16 * wr + lg * 4 + i;
            float rv = sigmoidf_(ar[i] + br_);
            float zv = sigmoidf_(az[i] + bz_);
            float nv = tanhf_(agi[i] + bgi + rv * (agh[i] + bgh));
            float hold = hfR[(size_t)row * 512 + hu];
            float hn = (1.f - zv) * nv + zv * hold;
            hfW[(size_t)row * 512 + hu] = hn;
            hbW[(size_t)row * 512 + hu] = f2bf(hn);
        }
    }
}

// ---------------------------------------------------------------------------
extern "C" void kernel_launch(void* const* d_in, const int* in_sizes, int n_in,
                              void* d_out, int out_size, void* d_ws,
                              size_t ws_size, hipStream_t stream) {
    (void)in_sizes; (void)n_in; (void)out_size;
    const float* x = (const float*)d_in[0];
    const float* eps = (const float*)d_in[2];
    const float* We1 = (const float*)d_in[3];
    const float* be1 = (const float*)d_in[4];
    const float* We2 = (const float*)d_in[5];
    const float* be2 = (const float*)d_in[6];
    const float* We3 = (const float*)d_in[7];
    const float* be3 = (const float*)d_in[8];
    const float* We41 = (const float*)d_in[9];
    const float* be41 = (const float*)d_in[10];
    const float* Wih = (const float*)d_in[11];
    const float* bih = (const float*)d_in[12];
    const float* Whh = (const float*)d_in[13];
    const float* bhh = (const float*)d_in[14];
    const float* Wf1 = (const float*)d_in[15];
    const float* bf1 = (const float*)d_in[16];
    const float* Wf2 = (const float*)d_in[17];
    const float* bf2 = (const float*)d_in[18];
    float* out = (float*)d_out;

    char* ws = (char*)d_ws;
    size_t off = 0;
    auto alloc = [&](size_t bytes) -> char* {
        char* p = ws + off;
        off += (bytes + 255) & ~(size_t)255;
        return p;
    };
    u16* xb = (u16*)alloc(2048ull * 4864 * 2);
    u16* We1b = (u16*)alloc(2048ull * 4864 * 2);
    u16* We2b = (u16*)alloc(1024ull * 2048 * 2);
    u16* We3b = (u16*)alloc(512ull * 1024 * 2);
    u16* We41b = (u16*)alloc(512ull * 512 * 2);
    u16* WB = (u16*)alloc(1536ull * 1024 * 2);
    u16* h1b = (u16*)alloc(2048ull * 2048 * 2);
    u16* h2b = (u16*)alloc(2048ull * 1024 * 2);
    u16* h3b = (u16*)alloc(2048ull * 512 * 2);
    u16* encb = (u16*)alloc(2048ull * 512 * 2);
    u16* hb0 = (u16*)alloc(2048ull * 512 * 2);
    u16* hb1 = (u16*)alloc(2048ull * 512 * 2);
    float* hf0 = (float*)alloc(2048ull * 512 * 4);
    float* hf1 = (float*)alloc(2048ull * 512 * 4);
    u16* Wf1p = (u16*)alloc(48ull * 512 * 2);
    u16* Wf2p = (u16*)alloc(512ull * 64 * 2);
    if (off > ws_size) {
        fill_const<<<(11010048 + 255) / 256, 256, 0, stream>>>(out, 11010048, 54321.0f);
        return;
    }
    u16* hb[2] = {hb0, hb1};
    float* hfl[2] = {hf0, hf1};

    // 1 setup launch + h init
    prep_all<<<8192, 256, 0, stream>>>(x, We1, We2, We3, We41, Wih, Whh, Wf1, Wf2,
                                       xb, We1b, We2b, We3b, We41b, WB, Wf1p, Wf2p);
    hipMemsetAsync(hb0, 0, 2048ull * 512 * 2, stream);
    hipMemsetAsync(hf0, 0, 2048ull * 512 * 4, stream);

    // encoder (bf16 MFMA), 4 launches
    gemm_bt<0><<<dim3(16, 16), 256, 0, stream>>>(xb, 4864, We1b, 4864, be1, h1b, 2048, 76, nullptr);
    gemm_bt<0><<<dim3(8, 16), 256, 0, stream>>>(h1b, 2048, We2b, 2048, be2, h2b, 1024, 32, nullptr);
    gemm_bt<0><<<dim3(4, 16), 256, 0, stream>>>(h2b, 1024, We3b, 1024, be3, h3b, 512, 16, nullptr);
    gemm_bt<1><<<dim3(4, 16), 256, 0, stream>>>(h3b, 512, We41b, 512, be41, encb, 512, 8, eps);

    // decoder: one fused kernel per step (XCD-swizzled, counted-vmcnt gates)
    gru_step<0><<<256, 1024, 0, stream>>>(encb, hb0, hf0, hb1, hf1, WB, bih,
                                          bhh, Wf1p, bf1, Wf2p, bf2, out, 0);
    for (int i = 1; i < 128; ++i) {
        int p = i & 1;
        gru_step<1><<<256, 1024, 0, stream>>>(nullptr, hb[p], hfl[p],
                                              hb[p ^ 1], hfl[p ^ 1], WB, bih,
                                              bhh, Wf1p, bf1, Wf2p, bf2, out,
                                              i - 1);
    }
    gru_step<2><<<32, 1024, 0, stream>>>(nullptr, hb0, hf0, nullptr, nullptr,
                                         WB, bih, bhh, Wf1p, bf1, Wf2p, bf2,
                                         out, 127);
}